// Round 11
// baseline (79.414 us; speedup 1.0000x reference)
//
#include <hip/hip_runtime.h>
#include <hip/hip_bf16.h>
#include <math.h>

// InteractionBlock R11 = R4 + REP=4 in-kernel repetition (DIAGNOSTIC ROUND).
// Our kernels have never been visible in the rocprof top-5 (harness 268MB
// ws-poison fills at ~41us own it). REP=4 inflates interact/gather dispatch
// durations ~4x so both surface with full counters. Side-effect-safe: list
// atomics run only on rep 0; every other write rewrites identical values.
// dur_us/rep gives per-kernel single-rep cost; next round reverts REP=1.

typedef __attribute__((ext_vector_type(8))) short short8;
typedef __attribute__((ext_vector_type(4))) float f32x4;
typedef __attribute__((ext_vector_type(4))) unsigned short u16x4;

#define DSTRIDE 72  // ushorts per data row (144 B, 16B-aligned)
#define REP 4       // diagnostic repetition factor

static __device__ __forceinline__ unsigned short f2bf(float f) {
  __hip_bfloat16 h = __float2bfloat16(f);
  return __builtin_bit_cast(unsigned short, h);
}
static __device__ __forceinline__ float bf2f(unsigned short s) {
  unsigned u = ((unsigned)s) << 16;
  return __builtin_bit_cast(float, u);
}

// ---- prep: head init + W2 -> bf16 B-fragments ----
__global__ __launch_bounds__(256)
void prep_kernel(const float* __restrict__ W2, unsigned short* __restrict__ w2f,
                 int* __restrict__ head, int N) {
  int gid = blockIdx.x * 256 + threadIdx.x;
  if (gid < N) head[gid] = -1;
  if (gid < 24 * 64) {
    int fi = gid >> 6, lane = gid & 63;
    int s = fi / 3, t = fi - 3 * s;
    int h = lane & 15, kq = lane >> 4;
    short8 pack;
    #pragma unroll
    for (int j = 0; j < 8; ++j) {
      int kg = s * 32 + kq * 8 + j;
      int kk = kg >> 4, c = kg & 15;
      pack[j] = (short)f2bf(W2[kk * 768 + t * 256 + c * 16 + h]);
    }
    *(short8*)&w2f[(size_t)gid * 8] = pack;
  }
}

// ---- K1: R4 body wrapped in REP loop (atomics only rep 0) ----
__global__ __launch_bounds__(256, 3)
void interact_kernel(const float* __restrict__ xfeat,
                     const float* __restrict__ coords,
                     const int* __restrict__ eidx,
                     const float* __restrict__ W1g,
                     const unsigned short* __restrict__ w2f,
                     unsigned short* __restrict__ data,  // [E][72] bf16
                     int* __restrict__ head,             // [N] init -1
                     int* __restrict__ next,             // [E]
                     int E)
{
  __shared__ __align__(16) float W1s[256];
  __shared__ float hsS[256 * 20];
  __shared__ __align__(16) unsigned short xsS[256 * 24];
  __shared__ int eS[256];
  __shared__ int wsum[4];

  const int tid  = threadIdx.x;
  const int lane = tid & 63, wid = tid >> 6;
  W1s[tid] = W1g[tid];
  __syncthreads();

  for (int rep = 0; rep < REP; ++rep) {
    const int e = blockIdx.x * 256 + tid;
    bool act = false;
    int src = 0, dst = 0;
    float rx = 0.f, ry = 0.f, rz = 0.f, d2 = 0.f;
    if (e < E) {
      src = eidx[e]; dst = eidx[E + e];
      rx = coords[3*src]   - coords[3*dst];
      ry = coords[3*src+1] - coords[3*dst+1];
      rz = coords[3*src+2] - coords[3*dst+2];
      d2 = rx*rx + ry*ry + rz*rz;
      act = (d2 > 0.0f) && (d2 < 36.0f);
    }
    unsigned long long bm = __ballot(act);
    int pfx = __popcll(bm & ((1ull << lane) - 1ull));
    if (lane == 0) wsum[wid] = __popcll(bm);
    __syncthreads();
    int base = 0;
    #pragma unroll
    for (int w = 0; w < 4; ++w) base += (w < wid) ? wsum[w] : 0;
    const int total = wsum[0] + wsum[1] + wsum[2] + wsum[3];
    const int cpos = base + pfx;

    if (act) {
      float dd  = sqrtf(d2);
      float inv = 1.0f / dd;
      float x = rx*inv, y = ry*inv, z = rz*inv;
      const float A1 = 0.48860251190291992f;
      const float A2 = 1.09254843059207907f;
      const float A3 = 0.63078313050504001f;
      unsigned short* dr = data + (size_t)e * DSTRIDE;
      short8 ys;
      ys[0] = (short)f2bf(A1*x);   ys[1] = (short)f2bf(A1*y);  ys[2] = (short)f2bf(A1*z);
      ys[3] = (short)f2bf(A2*x*z); ys[4] = (short)f2bf(A2*x*y);
      ys[5] = (short)f2bf(A3*(y*y - 0.5f*(x*x + z*z)));
      ys[6] = (short)f2bf(A2*y*z); ys[7] = (short)f2bf(0.5f*A2*(z*z - x*x));
      *(short8*)&dr[64] = ys;
      if (rep == 0) next[e] = atomicExch(&head[dst], e);   // only once

      float theta = 0.52359877559829887f * dd;
      float s1 = __sinf(theta), c1 = __cosf(theta);
      float snm = 0.0f, sn = s1;
      float4 hbv[4];
      #pragma unroll
      for (int q = 0; q < 4; ++q) hbv[q] = make_float4(0.f, 0.f, 0.f, 0.f);
      #pragma unroll
      for (int k = 0; k < 16; ++k) {
        #pragma unroll
        for (int q = 0; q < 4; ++q) {
          const float4 w = *((const float4*)&W1s[k*16 + q*4]);
          hbv[q].x = fmaf(sn, w.x, hbv[q].x);
          hbv[q].y = fmaf(sn, w.y, hbv[q].y);
          hbv[q].z = fmaf(sn, w.z, hbv[q].z);
          hbv[q].w = fmaf(sn, w.w, hbv[q].w);
        }
        float sp = 2.0f*c1*sn - snm;
        snm = sn; sn = sp;
      }
      const float scale1 = 2.30940107675850305f * inv * 0.25f;
      float* hrow = &hsS[cpos * 20];
      #pragma unroll
      for (int q = 0; q < 4; ++q) {
        float b[4] = {hbv[q].x, hbv[q].y, hbv[q].z, hbv[q].w};
        #pragma unroll
        for (int r = 0; r < 4; ++r) {
          float p = b[r] * scale1;
          hrow[q*4 + r] = 1.679177f * p / (1.0f + __expf(-p));
        }
      }
      unsigned short* xrow = &xsS[cpos * 24];
      #pragma unroll
      for (int cc = 0; cc < 4; ++cc) {
        float4 xv = *(const float4*)&xfeat[src*16 + cc*4];
        xrow[cc*4+0] = f2bf(xv.x); xrow[cc*4+1] = f2bf(xv.y);
        xrow[cc*4+2] = f2bf(xv.z); xrow[cc*4+3] = f2bf(xv.w);
      }
      eS[cpos] = e;
    }
    const int padded = (total + 15) & ~15;
    if (tid >= total && tid < padded) {
      #pragma unroll
      for (int j = 0; j < 16; ++j) hsS[tid*20 + j] = 0.0f;
      #pragma unroll
      for (int j = 0; j < 16; ++j) xsS[tid*24 + j] = 0;
    }
    __syncthreads();

    // ---- MFMA GEMM [padded,256] x [256,48] ----
    short8 bfr[8][3];
    #pragma unroll
    for (int s = 0; s < 8; ++s)
      #pragma unroll
      for (int t = 0; t < 3; ++t)
        bfr[s][t] = *(const short8*)&w2f[(size_t)((s*3 + t)*64 + lane) * 8];

    const int ngroups = padded >> 4;
    const int ma = lane & 15, kq = lane >> 4;
    const int c0 = (kq & 1) * 8;
    for (int g = wid; g < ngroups; g += 4) {
      const int cidx = g*16 + ma;
      const float* hrow = &hsS[cidx * 20];
      const unsigned short* xrow = &xsS[cidx * 24];
      float xsf[8];
      #pragma unroll
      for (int j = 0; j < 8; ++j) xsf[j] = bf2f(xrow[c0 + j]);

      f32x4 acc0 = {0,0,0,0}, acc1 = {0,0,0,0}, acc2 = {0,0,0,0};
      #pragma unroll
      for (int s = 0; s < 8; ++s) {
        const float hk = hrow[2*s + (kq >> 1)];
        short8 a;
        #pragma unroll
        for (int j = 0; j < 8; ++j) a[j] = (short)f2bf(hk * xsf[j]);
        acc0 = __builtin_amdgcn_mfma_f32_16x16x32_bf16(a, bfr[s][0], acc0, 0, 0, 0);
        acc1 = __builtin_amdgcn_mfma_f32_16x16x32_bf16(a, bfr[s][1], acc1, 0, 0, 0);
        acc2 = __builtin_amdgcn_mfma_f32_16x16x32_bf16(a, bfr[s][2], acc2, 0, 0, 0);
      }
      const float sc = 0.00390625f;  // 1/256
      #pragma unroll
      for (int r = 0; r < 4; ++r) {
        const int cr = g*16 + kq*4 + r;
        if (cr < total) {
          unsigned short* dr = data + (size_t)eS[cr] * DSTRIDE;
          u16x4 vv;
          vv[0] = f2bf(acc0[r] * sc);
          vv[1] = f2bf(acc1[r] * sc);
          vv[2] = f2bf(acc2[r] * sc);
          vv[3] = 0;
          *(u16x4*)&dr[ma * 4] = vv;
        }
      }
    }
    __syncthreads();                       // protect LDS before next rep
    asm volatile("" ::: "memory");         // force re-execution of loads
  }
}

// ---- K2: gather, body wrapped in REP loop (writes identical values) ----
__global__ __launch_bounds__(256)
void gather_kernel(const unsigned short* __restrict__ data,
                   const int* __restrict__ head,
                   const int* __restrict__ next,
                   float* __restrict__ out, int N)
{
  int gid = blockIdx.x * 256 + threadIdx.x;
  int node = gid >> 4, h = gid & 15;
  if (node >= N) return;

  for (int rep = 0; rep < REP; ++rep) {
    float a0 = 0.f;
    float a10 = 0.f, a11 = 0.f, a12 = 0.f;
    float a20 = 0.f, a21 = 0.f, a22 = 0.f, a23 = 0.f, a24 = 0.f;

    int p = head[node];
    while (p >= 0) {
      const unsigned short* dr = data + (size_t)p * DSTRIDE;
      int pn = next[p];
      u16x4 vv = *(const u16x4*)&dr[h * 4];
      short8 yv = *(const short8*)&dr[64];
      float v0 = bf2f(vv[0]), v1 = bf2f(vv[1]), v2 = bf2f(vv[2]);
      a0  += v0;
      a10 = fmaf(v1, bf2f((unsigned short)yv[0]), a10);
      a11 = fmaf(v1, bf2f((unsigned short)yv[1]), a11);
      a12 = fmaf(v1, bf2f((unsigned short)yv[2]), a12);
      a20 = fmaf(v2, bf2f((unsigned short)yv[3]), a20);
      a21 = fmaf(v2, bf2f((unsigned short)yv[4]), a21);
      a22 = fmaf(v2, bf2f((unsigned short)yv[5]), a22);
      a23 = fmaf(v2, bf2f((unsigned short)yv[6]), a23);
      a24 = fmaf(v2, bf2f((unsigned short)yv[7]), a24);
      p = pn;
    }

    float* o = out + (size_t)node * 144;
    o[h] = a0 * 0.28209479177387814f;
    o[16 + h*3 + 0] = a10;
    o[16 + h*3 + 1] = a11;
    o[16 + h*3 + 2] = a12;
    o[64 + h*5 + 0] = a20;
    o[64 + h*5 + 1] = a21;
    o[64 + h*5 + 2] = a22;
    o[64 + h*5 + 3] = a23;
    o[64 + h*5 + 4] = a24;
    asm volatile("" ::: "memory");         // force re-execution per rep
  }
}

extern "C" void kernel_launch(void* const* d_in, const int* in_sizes, int n_in,
                              void* d_out, int out_size, void* d_ws, size_t ws_size,
                              hipStream_t stream) {
  const float* xfeat  = (const float*)d_in[0];
  const float* coords = (const float*)d_in[1];
  const int*   eidx   = (const int*)d_in[2];
  const float* W1     = (const float*)d_in[3];
  const float* W2     = (const float*)d_in[4];
  float* out = (float*)d_out;

  const int E = in_sizes[2] / 2;
  const int N = out_size / 144;

  char* ws = (char*)d_ws;
  size_t off_head = (size_t)E * DSTRIDE * sizeof(unsigned short);
  size_t off_next = off_head + (size_t)((N + 3) & ~3) * sizeof(int);
  size_t off_w2f  = off_next + (size_t)E * sizeof(int);
  unsigned short* data = (unsigned short*)ws;
  int* head = (int*)(ws + off_head);
  int* next = (int*)(ws + off_next);
  unsigned short* w2f = (unsigned short*)(ws + off_w2f);

  int pblk = (N + 255) / 256;
  if (pblk < 6) pblk = 6;
  prep_kernel<<<pblk, 256, 0, stream>>>(W2, w2f, head, N);
  interact_kernel<<<(E + 255) / 256, 256, 0, stream>>>(xfeat, coords, eidx, W1,
                                                       w2f, data, head, next, E);
  gather_kernel<<<(N * 16 + 255) / 256, 256, 0, stream>>>(data, head, next, out, N);
}

// Round 12
// 37.809 us; speedup vs baseline: 2.1004x; 2.1004x over previous
//
#include <hip/hip_runtime.h>
#include <hip/hip_bf16.h>
#include <math.h>

// InteractionBlock R12: interact reworked to single-wave blocks (64 thr, 16
// edges/wave, 4 roles/edge), NO compaction, NO cross-wave barrier coupling.
// R11 diagnostic: interact ~24us of the 37.4 total, 78% stall (VALUBusy 22%,
// Occ 20%): block-wide barrier made 4 waves wait on each other's cold scattered
// loads at 2.44 waves/SIMD. Single-wave blocks -> each wave independent; grid
// 10000 blocks supplies 16+ waves/CU; inactive edges ride the MFMA (4% util)
// with stores predicated by ballot mask.
//  prep:   head[]=-1 + pack W2 -> pre-swizzled bf16 MFMA B-fragments.
//  K1:     16 edges/wave: geometry/bessel (role q: h[4q..4q+3], xfeat quad q)
//          -> wave-local LDS -> 24 MFMAs (B streamed from L1-hot w2f)
//          -> factored bf16 rows data[e]={v[16][4],Y1..8} + per-dst list.
//  K2:     per-node list gather, expand msg = v_l[h]*Y[m], write out once.

typedef __attribute__((ext_vector_type(8))) short short8;
typedef __attribute__((ext_vector_type(4))) float f32x4;
typedef __attribute__((ext_vector_type(4))) unsigned short u16x4;

#define DSTRIDE 72  // ushorts per data row (144 B, 16B-aligned)

static __device__ __forceinline__ unsigned short f2bf(float f) {
  __hip_bfloat16 h = __float2bfloat16(f);
  return __builtin_bit_cast(unsigned short, h);
}
static __device__ __forceinline__ float bf2f(unsigned short s) {
  unsigned u = ((unsigned)s) << 16;
  return __builtin_bit_cast(float, u);
}

// ---- prep: head init + W2 -> bf16 B-fragments ----
// frag fi = s*3+t; entry (fi,lane,j): k_global = s*32+(lane>>4)*8+j, n = t*16+(lane&15)
// W2r[k][n] = W2[kk*768 + t*256 + c*16 + h], kk=k>>4, c=k&15, h=lane&15
__global__ __launch_bounds__(256)
void prep_kernel(const float* __restrict__ W2, unsigned short* __restrict__ w2f,
                 int* __restrict__ head, int N) {
  int gid = blockIdx.x * 256 + threadIdx.x;
  if (gid < N) head[gid] = -1;
  if (gid < 24 * 64) {
    int fi = gid >> 6, lane = gid & 63;
    int s = fi / 3, t = fi - 3 * s;
    int h = lane & 15, kq = lane >> 4;
    short8 pack;
    #pragma unroll
    for (int j = 0; j < 8; ++j) {
      int kg = s * 32 + kq * 8 + j;
      int kk = kg >> 4, c = kg & 15;
      pack[j] = (short)f2bf(W2[kk * 768 + t * 256 + c * 16 + h]);
    }
    *(short8*)&w2f[(size_t)gid * 8] = pack;
  }
}

// ---- K1: one wave per block, 16 edges/wave, 4 roles/edge ----
__global__ __launch_bounds__(64, 4)
void interact_kernel(const float* __restrict__ xfeat,
                     const float* __restrict__ coords,
                     const int* __restrict__ eidx,
                     const float* __restrict__ W1g,
                     const unsigned short* __restrict__ w2f,
                     unsigned short* __restrict__ data,  // [E][72] bf16
                     int* __restrict__ head,             // [N] init -1
                     int* __restrict__ next,             // [E]
                     int E)
{
  __shared__ __align__(16) float W1s[256];
  __shared__ float hsS[16 * 20];                        // stride 20 f32 (80B)
  __shared__ __align__(16) unsigned short xsS[16 * 24]; // stride 24 ush (48B)

  const int tid = threadIdx.x;          // 0..63 (one wave)
  const int q   = tid & 3;              // role within edge
  const int el  = tid >> 2;             // edge slot 0..15
  *(float4*)&W1s[tid * 4] = *(const float4*)&W1g[tid * 4];

  const int e = blockIdx.x * 16 + el;
  bool act = false;
  int src = 0, dst = 0;
  float rx = 0.f, ry = 0.f, rz = 0.f, d2 = 0.f;
  if (e < E) {
    src = eidx[e]; dst = eidx[E + e];
    rx = coords[3*src]   - coords[3*dst];
    ry = coords[3*src+1] - coords[3*dst+1];
    rz = coords[3*src+2] - coords[3*dst+2];
    d2 = rx*rx + ry*ry + rz*rz;
    act = (d2 > 0.0f) && (d2 < 36.0f);
  }
  // role q loads xfeat quad q of src row (coalesced 16B)
  const float4 xq = *(const float4*)&xfeat[src*16 + q*4];

  const unsigned long long bm = __ballot(act);  // bit 4*el set iff edge el active

  if (act) {
    float dd  = sqrtf(d2);
    float inv = 1.0f / dd;
    if (q == 0) {
      float x = rx*inv, y = ry*inv, z = rz*inv;
      const float A1 = 0.48860251190291992f;  // sqrt(3)/sqrt(4pi)
      const float A2 = 1.09254843059207907f;  // sqrt(15)/sqrt(4pi)
      const float A3 = 0.63078313050504001f;  // sqrt(5)/sqrt(4pi)
      unsigned short* dr = data + (size_t)e * DSTRIDE;
      short8 ys;
      ys[0] = (short)f2bf(A1*x);   ys[1] = (short)f2bf(A1*y);  ys[2] = (short)f2bf(A1*z);
      ys[3] = (short)f2bf(A2*x*z); ys[4] = (short)f2bf(A2*x*y);
      ys[5] = (short)f2bf(A3*(y*y - 0.5f*(x*x + z*z)));
      ys[6] = (short)f2bf(A2*y*z); ys[7] = (short)f2bf(0.5f*A2*(z*z - x*x));
      *(short8*)&dr[64] = ys;
      next[e] = atomicExch(&head[dst], e);   // device-scope
    }
    // bessel -> hidden: role q computes h[4q..4q+3]
    float theta = 0.52359877559829887f * dd;   // pi/6 * d
    float s1 = __sinf(theta), c1 = __cosf(theta);
    float snm = 0.0f, sn = s1;
    float4 hb = make_float4(0.f, 0.f, 0.f, 0.f);
    #pragma unroll
    for (int k = 0; k < 16; ++k) {
      const float4 w = *((const float4*)&W1s[k*16 + q*4]);
      hb.x = fmaf(sn, w.x, hb.x);
      hb.y = fmaf(sn, w.y, hb.y);
      hb.z = fmaf(sn, w.z, hb.z);
      hb.w = fmaf(sn, w.w, hb.w);
      float sp = 2.0f*c1*sn - snm;
      snm = sn; sn = sp;
    }
    const float scale1 = 2.30940107675850305f * inv * 0.25f;
    float4 hv;
    {
      float b[4] = {hb.x, hb.y, hb.z, hb.w};
      float* op = (float*)&hv;
      #pragma unroll
      for (int r = 0; r < 4; ++r) {
        float p = b[r] * scale1;
        op[r] = 1.679177f * p / (1.0f + __expf(-p));
      }
    }
    *(float4*)&hsS[el * 20 + q * 4] = hv;
    u16x4 xp;
    xp[0] = f2bf(xq.x); xp[1] = f2bf(xq.y); xp[2] = f2bf(xq.z); xp[3] = f2bf(xq.w);
    *(u16x4*)&xsS[el * 24 + q * 4] = xp;
  } else {
    // zero this edge's slice so MFMA rows are finite (defensive; row-local anyway)
    *(float4*)&hsS[el * 20 + q * 4] = make_float4(0.f, 0.f, 0.f, 0.f);
    u16x4 z; z[0] = 0; z[1] = 0; z[2] = 0; z[3] = 0;
    *(u16x4*)&xsS[el * 24 + q * 4] = z;
  }
  __syncthreads();   // single-wave block: trivially cheap, orders LDS

  // ---- MFMA GEMM [16,256] x [256,48], B-frags streamed from L1-hot w2f ----
  const int ma = tid & 15, kq = tid >> 4;
  const int c0 = (kq & 1) * 8;
  const float* hrow = &hsS[ma * 20];
  const unsigned short* xrow = &xsS[ma * 24];
  float xsf[8];
  #pragma unroll
  for (int j = 0; j < 8; ++j) xsf[j] = bf2f(xrow[c0 + j]);

  f32x4 acc0 = {0,0,0,0}, acc1 = {0,0,0,0}, acc2 = {0,0,0,0};
  #pragma unroll
  for (int s = 0; s < 8; ++s) {
    const float hk = hrow[2*s + (kq >> 1)];
    short8 a;
    #pragma unroll
    for (int j = 0; j < 8; ++j) a[j] = (short)f2bf(hk * xsf[j]);
    const short8 b0 = *(const short8*)&w2f[(size_t)((s*3 + 0)*64 + tid) * 8];
    const short8 b1 = *(const short8*)&w2f[(size_t)((s*3 + 1)*64 + tid) * 8];
    const short8 b2 = *(const short8*)&w2f[(size_t)((s*3 + 2)*64 + tid) * 8];
    acc0 = __builtin_amdgcn_mfma_f32_16x16x32_bf16(a, b0, acc0, 0, 0, 0);
    acc1 = __builtin_amdgcn_mfma_f32_16x16x32_bf16(a, b1, acc1, 0, 0, 0);
    acc2 = __builtin_amdgcn_mfma_f32_16x16x32_bf16(a, b2, acc2, 0, 0, 0);
  }
  // D layout: row = kq*4 + r, col = lane&15  (m89-verified)
  const float sc = 0.00390625f;  // 1/256
  #pragma unroll
  for (int r = 0; r < 4; ++r) {
    const int er = kq*4 + r;                       // edge slot of this D row
    if ((bm >> (4*er)) & 1ull) {
      unsigned short* dr = data + (size_t)(blockIdx.x*16 + er) * DSTRIDE;
      u16x4 vv;
      vv[0] = f2bf(acc0[r] * sc);
      vv[1] = f2bf(acc1[r] * sc);
      vv[2] = f2bf(acc2[r] * sc);
      vv[3] = 0;
      *(u16x4*)&dr[ma * 4] = vv;
    }
  }
}

// ---- K2: gather (16 threads per node walk the dst list) ----
__global__ __launch_bounds__(256)
void gather_kernel(const unsigned short* __restrict__ data,
                   const int* __restrict__ head,
                   const int* __restrict__ next,
                   float* __restrict__ out, int N)
{
  int gid = blockIdx.x * 256 + threadIdx.x;
  int node = gid >> 4, h = gid & 15;
  if (node >= N) return;

  float a0 = 0.f;
  float a10 = 0.f, a11 = 0.f, a12 = 0.f;
  float a20 = 0.f, a21 = 0.f, a22 = 0.f, a23 = 0.f, a24 = 0.f;

  int p = head[node];
  while (p >= 0) {
    const unsigned short* dr = data + (size_t)p * DSTRIDE;
    int pn = next[p];
    u16x4 vv = *(const u16x4*)&dr[h * 4];
    short8 yv = *(const short8*)&dr[64];
    float v0 = bf2f(vv[0]), v1 = bf2f(vv[1]), v2 = bf2f(vv[2]);
    a0  += v0;
    a10 = fmaf(v1, bf2f((unsigned short)yv[0]), a10);
    a11 = fmaf(v1, bf2f((unsigned short)yv[1]), a11);
    a12 = fmaf(v1, bf2f((unsigned short)yv[2]), a12);
    a20 = fmaf(v2, bf2f((unsigned short)yv[3]), a20);
    a21 = fmaf(v2, bf2f((unsigned short)yv[4]), a21);
    a22 = fmaf(v2, bf2f((unsigned short)yv[5]), a22);
    a23 = fmaf(v2, bf2f((unsigned short)yv[6]), a23);
    a24 = fmaf(v2, bf2f((unsigned short)yv[7]), a24);
    p = pn;
  }

  float* o = out + (size_t)node * 144;
  o[h] = a0 * 0.28209479177387814f;   // Y0 constant folded here
  o[16 + h*3 + 0] = a10;
  o[16 + h*3 + 1] = a11;
  o[16 + h*3 + 2] = a12;
  o[64 + h*5 + 0] = a20;
  o[64 + h*5 + 1] = a21;
  o[64 + h*5 + 2] = a22;
  o[64 + h*5 + 3] = a23;
  o[64 + h*5 + 4] = a24;
}

extern "C" void kernel_launch(void* const* d_in, const int* in_sizes, int n_in,
                              void* d_out, int out_size, void* d_ws, size_t ws_size,
                              hipStream_t stream) {
  const float* xfeat  = (const float*)d_in[0];
  const float* coords = (const float*)d_in[1];
  const int*   eidx   = (const int*)d_in[2];
  const float* W1     = (const float*)d_in[3];
  const float* W2     = (const float*)d_in[4];
  float* out = (float*)d_out;

  const int E = in_sizes[2] / 2;
  const int N = out_size / 144;

  // ws layout (all 16B-aligned): data bf16[E][72] | head[N pad4] | next[E] | w2f[12288 ush]
  char* ws = (char*)d_ws;
  size_t off_head = (size_t)E * DSTRIDE * sizeof(unsigned short);
  size_t off_next = off_head + (size_t)((N + 3) & ~3) * sizeof(int);
  size_t off_w2f  = off_next + (size_t)E * sizeof(int);
  unsigned short* data = (unsigned short*)ws;
  int* head = (int*)(ws + off_head);
  int* next = (int*)(ws + off_next);
  unsigned short* w2f = (unsigned short*)(ws + off_w2f);

  int pblk = (N + 255) / 256;
  if (pblk < 6) pblk = 6;
  prep_kernel<<<pblk, 256, 0, stream>>>(W2, w2f, head, N);
  interact_kernel<<<(E + 15) / 16, 64, 0, stream>>>(xfeat, coords, eidx, W1,
                                                    w2f, data, head, next, E);
  gather_kernel<<<(N * 16 + 255) / 256, 256, 0, stream>>>(data, head, next, out, N);
}